// Round 10
// baseline (155.109 us; speedup 1.0000x reference)
//
#include <hip/hip_runtime.h>
#include <math.h>

#define BATCH 2
#define CIN   256
#define COUT  256
#define COFF  256
#define HWPIX 4096
#define CKTOT 2304
#define VSTR  40            // V row stride in shorts (80 B)
#define VSLOT (288 * VSTR)  // one chunk buffer: 9 taps x 32 px rows
#define PH    66            // padded feat spatial dim
#define PHW   4356          // 66*66
#define NKG   12            // conv_om K-split

typedef __attribute__((ext_vector_type(8))) short short8;
typedef __attribute__((ext_vector_type(4))) float float4v;

__device__ __forceinline__ unsigned short f2bf(float f) {
    unsigned u = __float_as_uint(f);
    unsigned r = (u + 0x7FFFu + ((u >> 16) & 1u)) >> 16;   // RNE
    return (unsigned short)r;
}
__device__ __forceinline__ unsigned short f2bf_trunc(float f) {
    return (unsigned short)(__float_as_uint(f) >> 16);
}
__device__ __forceinline__ float bf2f(unsigned short h) {
    return __uint_as_float(((unsigned)h) << 16);
}

// ---------------------------------------------------------------------------
// prep: ONE kernel, blockIdx regions (unchanged from r9)
// ---------------------------------------------------------------------------
__global__ __launch_bounds__(256) void prep_kernel(
    const float* __restrict__ x, const float* __restrict__ feat,
    const float* __restrict__ wdcn, const float* __restrict__ wom,
    unsigned short* __restrict__ xTh,
    unsigned short* __restrict__ fh, unsigned short* __restrict__ fl,
    unsigned short* __restrict__ whi,
    unsigned short* __restrict__ wohi, unsigned short* __restrict__ wolo)
{
    const int bid = blockIdx.x;
    const int tid = threadIdx.x;

    if (bid < 4096) {
        const bool isx = bid < 2048;
        const int lb = isx ? bid : bid - 2048;
        const int b  = lb >> 10;
        const int r  = lb & 1023;
        const int pt = r >> 3;       // 128 px tiles of 32
        const int ct = r & 7;        // 8 ch tiles of 32
        __shared__ float t[32][33];
        const int tx = tid & 31, ty = tid >> 5;
        const float* src = isx ? x : feat;
        const float* sb = src + ((size_t)b * 256 + ct * 32) * HWPIX + pt * 32;
#pragma unroll
        for (int i = ty; i < 32; i += 8)
            t[i][tx] = sb[(size_t)i * HWPIX + tx];
        __syncthreads();
        if (isx) {
            unsigned short* ob = xTh + ((size_t)b * HWPIX + pt * 32) * 256 + ct * 32;
#pragma unroll
            for (int i = ty; i < 32; i += 8)
                ob[(size_t)i * 256 + tx] = f2bf(t[tx][i]);
        } else {
#pragma unroll
            for (int i = ty; i < 32; i += 8) {
                int p = pt * 32 + i;
                int row = (p >> 6) + 1, col = (p & 63) + 1;
                size_t o = ((size_t)b * PHW + row * PH + col) * 256 + ct * 32 + tx;
                float v = t[tx][i];
                unsigned short hi = f2bf(v);
                fh[o] = hi;
                fl[o] = f2bf_trunc(v - bf2f(hi));
            }
        }
    } else if (bid < 6400) {
        int gid = (bid - 4096) * 256 + tid;    // 0..589823
        int cc  = gid & 31;
        int co  = (gid >> 5) & 255;
        int kcb = gid >> 13;
        int k   = kcb >> 3;
        int cb  = kcb & 7;
        float w = wdcn[((size_t)co * 256 + cb * 32 + cc) * 9 + k];
        whi[gid] = f2bf(w);
    } else if (bid < 6688) {
        int gid = (bid - 6400) * 256 + tid;    // 0..73727
        int cc  = gid & 31;
        int co  = (gid >> 5) & 31;
        int kcb = gid >> 10;
        int k   = kcb >> 3;
        int cb  = kcb & 7;
        float w = 0.0f;
        if (co < 27) w = wom[(size_t)co * CKTOT + (cb * 32 + cc) * 9 + k];
        unsigned short hi = f2bf(w);
        wohi[gid] = hi;
        wolo[gid] = f2bf_trunc(w - bf2f(hi));
    } else {
        int idx = (bid - 6688) * 256 + tid;    // < 133120 = 2*260*256 exactly
        int b = idx / 66560;
        int r = idx - b * 66560;
        int pidx = r >> 8;                     // 0..259 border cells
        int c = r & 255;
        int row, col;
        if (pidx < 66)       { row = 0;           col = pidx; }
        else if (pidx < 132) { row = 65;          col = pidx - 66; }
        else if (pidx < 196) { row = pidx - 131;  col = 0; }
        else                 { row = pidx - 195;  col = 65; }
        size_t o = ((size_t)b * PHW + row * PH + col) * 256 + c;
        fh[o] = 0;
        fl[o] = 0;
    }
}

// ---------------------------------------------------------------------------
// conv_om via MFMA bf16x3 (pre-split feat), K-split x12 (unchanged from r9)
// ---------------------------------------------------------------------------
__global__ __launch_bounds__(256) void conv_om_mfma_kernel(
    const unsigned short* __restrict__ fh,     // [2][4356][256] bf16 hi
    const unsigned short* __restrict__ fl,     // [2][4356][256] bf16 lo
    const unsigned short* __restrict__ wohi,
    const unsigned short* __restrict__ wolo,
    float* __restrict__ om12)                  // [12][2][27][4096]
{
    const int y  = blockIdx.x;     // 0..63
    const int kg = blockIdx.y;     // 0..11
    const int b  = blockIdx.z;
    const int tid = threadIdx.x;
    const int wv  = tid >> 6;
    const int lane = tid & 63;
    const int l15 = lane & 15;
    const int q   = lane >> 4;
    const int xg  = wv * 16 + l15;

    float4v acc[2];
    acc[0] = (float4v)0.0f;
    acc[1] = (float4v)0.0f;

    const unsigned short* fhb = fh + (size_t)b * PHW * 256;
    const unsigned short* flb = fl + (size_t)b * PHW * 256;

#pragma unroll 3
    for (int i = 0; i < 6; ++i) {
        int kcb = kg * 6 + i;
        int k  = kcb >> 3;
        int cb = kcb & 7;
        size_t s = ((size_t)((y + k / 3) * PH + xg + k % 3)) * 256 + cb * 32 + q * 8;
        short8 bh = *(const short8*)(fhb + s);
        short8 bl = *(const short8*)(flb + s);
        short8 ah[2], al[2];
#pragma unroll
        for (int t = 0; t < 2; ++t) {
            size_t off = ((size_t)kcb * 32 + t * 16 + l15) * 32 + q * 8;
            ah[t] = *(const short8*)(wohi + off);
            al[t] = *(const short8*)(wolo + off);
        }
#pragma unroll
        for (int t = 0; t < 2; ++t) {
            acc[t] = __builtin_amdgcn_mfma_f32_16x16x32_bf16(ah[t], bh, acc[t], 0, 0, 0);
            acc[t] = __builtin_amdgcn_mfma_f32_16x16x32_bf16(ah[t], bl, acc[t], 0, 0, 0);
            acc[t] = __builtin_amdgcn_mfma_f32_16x16x32_bf16(al[t], bh, acc[t], 0, 0, 0);
        }
    }

    const int p = y * 64 + xg;
    float* ob = om12 + (size_t)(kg * 2 + b) * 27 * HWPIX;
#pragma unroll
    for (int t = 0; t < 2; ++t) {
#pragma unroll
        for (int r = 0; r < 4; ++r) {
            int co = t * 16 + q * 4 + r;
            if (co < 27) ob[co * HWPIX + p] = acc[t][r];
        }
    }
}

// ---------------------------------------------------------------------------
// dcn v8: producer/consumer wave specialization. Tile 128co x 32px/block.
// Waves {0,1}=group0, {2,3}=group1. Step c: group (c&1) runs the 9-tap MFMA
// chain for chunk c from V[c&1] while the other group stages chunk c+1 into
// V[(c+1)&1]. Each group accumulates partials for the FULL tile over its
// chunks (g0: even cb, g1: odd cb); combined through LDS at the end.
// ---------------------------------------------------------------------------
__global__ __launch_bounds__(256) void dcn_mfma_kernel(
    const unsigned short* __restrict__ xTh,    // [2][4096][256] bf16
    const float* __restrict__ om12,            // [12][2][27][4096]
    const unsigned short* __restrict__ whi,    // [72][256][32] bf16 hi
    const float* __restrict__ bom,             // [27]
    const float* __restrict__ bdcn,            // [256]
    float* __restrict__ out)                   // [2][256][4096]
{
    const int tid = threadIdx.x;
    const int y   = blockIdx.x >> 1;           // 0..63
    const int xh  = blockIdx.x & 1;            // 0..1 (32-px halves)
    const int cog = blockIdx.y;                // 0..1 (co halves)
    const int b   = blockIdx.z;

    __shared__ float4 s_wt[288];               // masked bilinear weights
    __shared__ int4   s_ix[288];               // clamped corner indices
    __shared__ unsigned short V[2 * VSLOT];    // double-buffered B chunks

    // ---- prologue: sum 12 om partials + bias; bilinear weights + indices ----
    for (int idx = tid; idx < 288; idx += 256) {
        int k   = idx >> 5;
        int pxl = idx & 31;
        int xg  = xh * 32 + pxl;
        int p   = y * 64 + xg;
        float dy = bom[2 * k], dx = bom[2 * k + 1], mm = bom[18 + k];
#pragma unroll
        for (int g = 0; g < NKG; ++g) {
            const float* ob = om12 + (size_t)(g * 2 + b) * 27 * HWPIX;
            dy += ob[(2 * k) * HWPIX + p];
            dx += ob[(2 * k + 1) * HWPIX + p];
            mm += ob[(18 + k) * HWPIX + p];
        }
        float ys = (float)(y  - 1 + (k / 3)) + dy;
        float xs = (float)(xg - 1 + (k % 3)) + dx;
        float y0f = floorf(ys), x0f = floorf(xs);
        int y0 = (int)y0f, x0 = (int)x0f;
        float ly = ys - y0f, lx = xs - x0f;
        float m  = 1.0f / (1.0f + expf(-mm));
        bool yv0 = ((unsigned)y0 < 64u), yv1 = ((unsigned)(y0 + 1) < 64u);
        bool xv0 = ((unsigned)x0 < 64u), xv1 = ((unsigned)(x0 + 1) < 64u);
        int i00 = y0 * 64 + x0;
        float4 wt;
        int4 ix;
        wt.x = (yv0 && xv0) ? (1.0f - ly) * (1.0f - lx) * m : 0.0f;
        wt.y = (yv0 && xv1) ? (1.0f - ly) * lx * m          : 0.0f;
        wt.z = (yv1 && xv0) ? ly * (1.0f - lx) * m          : 0.0f;
        wt.w = (yv1 && xv1) ? ly * lx * m                   : 0.0f;
        ix.x = (yv0 && xv0) ? i00      : 0;
        ix.y = (yv0 && xv1) ? i00 + 1  : 0;
        ix.z = (yv1 && xv0) ? i00 + 64 : 0;
        ix.w = (yv1 && xv1) ? i00 + 65 : 0;
        s_wt[idx] = wt;
        s_ix[idx] = ix;
    }
    __syncthreads();

    const int grp  = tid >> 7;         // group 0: waves 0-1, group 1: waves 2-3
    const int gw   = (tid >> 6) & 1;   // wave within group -> co base gw*64
    const int lane = tid & 63;
    const int l15  = lane & 15;
    const int q    = lane >> 4;

    // staging map (within a 128-thread group): cg = 4 ch, spx = 16 px
    const int cg  = tid & 7;
    const int spx = (tid >> 3) & 15;

    float4v acc[4][2];                 // 4 co-tiles (64 co) x 2 px-tiles
#pragma unroll
    for (int t = 0; t < 4; ++t)
#pragma unroll
        for (int p = 0; p < 2; ++p) acc[t][p] = (float4v)0.0f;

    const unsigned short* xb = xTh + ((size_t)b << 12) * 256;
    const unsigned short* xc = xb + cg * 4;    // + cb*32 per chunk

    // ---- pre-step: group 0 stages chunk 0 into V[0] ----
    if (grp == 0) {
        const unsigned short* xs0 = xc + 0 * 32;
#pragma unroll 3
        for (int it = 0; it < 18; ++it) {
            int k  = it >> 1;
            int px = (it & 1) * 16 + spx;
            int cidx = k * 32 + px;
            float4 wt = s_wt[cidx];
            int4   ix = s_ix[cidx];
            ushort4 u00 = *(const ushort4*)(xs0 + (size_t)ix.x * 256);
            ushort4 u01 = *(const ushort4*)(xs0 + (size_t)ix.y * 256);
            ushort4 u10 = *(const ushort4*)(xs0 + (size_t)ix.z * 256);
            ushort4 u11 = *(const ushort4*)(xs0 + (size_t)ix.w * 256);
            float v0 = wt.x * bf2f(u00.x) + wt.y * bf2f(u01.x) + wt.z * bf2f(u10.x) + wt.w * bf2f(u11.x);
            float v1 = wt.x * bf2f(u00.y) + wt.y * bf2f(u01.y) + wt.z * bf2f(u10.y) + wt.w * bf2f(u11.y);
            float v2 = wt.x * bf2f(u00.z) + wt.y * bf2f(u01.z) + wt.z * bf2f(u10.z) + wt.w * bf2f(u11.z);
            float v3 = wt.x * bf2f(u00.w) + wt.y * bf2f(u01.w) + wt.z * bf2f(u10.w) + wt.w * bf2f(u11.w);
            uint2 hv = make_uint2((unsigned)f2bf(v0) | ((unsigned)f2bf(v1) << 16),
                                  (unsigned)f2bf(v2) | ((unsigned)f2bf(v3) << 16));
            *(uint2*)&V[cidx * VSTR + cg * 4] = hv;
        }
    }
    __syncthreads();

    for (int c = 0; c < 8; ++c) {
        if ((c & 1) == grp) {
            // ---- consume chunk c from V[c&1] ----
            const unsigned short* Vc = V + (c & 1) * VSLOT;
#pragma unroll 3
            for (int k = 0; k < 9; ++k) {
                const int kcb = k * 8 + c;
                size_t base = ((size_t)kcb * 256 + cog * 128 + gw * 64 + l15) * 32 + q * 8;
                short8 a0 = *(const short8*)(whi + base);
                short8 a1 = *(const short8*)(whi + base + 16 * 32);
                short8 a2 = *(const short8*)(whi + base + 32 * 32);
                short8 a3 = *(const short8*)(whi + base + 48 * 32);
                short8 b0 = *(const short8*)&Vc[(k * 32 + l15) * VSTR + q * 8];
                short8 b1 = *(const short8*)&Vc[(k * 32 + 16 + l15) * VSTR + q * 8];
                acc[0][0] = __builtin_amdgcn_mfma_f32_16x16x32_bf16(a0, b0, acc[0][0], 0, 0, 0);
                acc[0][1] = __builtin_amdgcn_mfma_f32_16x16x32_bf16(a0, b1, acc[0][1], 0, 0, 0);
                acc[1][0] = __builtin_amdgcn_mfma_f32_16x16x32_bf16(a1, b0, acc[1][0], 0, 0, 0);
                acc[1][1] = __builtin_amdgcn_mfma_f32_16x16x32_bf16(a1, b1, acc[1][1], 0, 0, 0);
                acc[2][0] = __builtin_amdgcn_mfma_f32_16x16x32_bf16(a2, b0, acc[2][0], 0, 0, 0);
                acc[2][1] = __builtin_amdgcn_mfma_f32_16x16x32_bf16(a2, b1, acc[2][1], 0, 0, 0);
                acc[3][0] = __builtin_amdgcn_mfma_f32_16x16x32_bf16(a3, b0, acc[3][0], 0, 0, 0);
                acc[3][1] = __builtin_amdgcn_mfma_f32_16x16x32_bf16(a3, b1, acc[3][1], 0, 0, 0);
            }
        } else if (c < 7) {
            // ---- stage chunk c+1 into V[(c+1)&1] ----
            const int cc = c + 1;
            unsigned short* Vd = V + (cc & 1) * VSLOT;
            const unsigned short* xs0 = xc + cc * 32;
#pragma unroll 3
            for (int it = 0; it < 18; ++it) {
                int k  = it >> 1;
                int px = (it & 1) * 16 + spx;
                int cidx = k * 32 + px;
                float4 wt = s_wt[cidx];
                int4   ix = s_ix[cidx];
                ushort4 u00 = *(const ushort4*)(xs0 + (size_t)ix.x * 256);
                ushort4 u01 = *(const ushort4*)(xs0 + (size_t)ix.y * 256);
                ushort4 u10 = *(const ushort4*)(xs0 + (size_t)ix.z * 256);
                ushort4 u11 = *(const ushort4*)(xs0 + (size_t)ix.w * 256);
                float v0 = wt.x * bf2f(u00.x) + wt.y * bf2f(u01.x) + wt.z * bf2f(u10.x) + wt.w * bf2f(u11.x);
                float v1 = wt.x * bf2f(u00.y) + wt.y * bf2f(u01.y) + wt.z * bf2f(u10.y) + wt.w * bf2f(u11.y);
                float v2 = wt.x * bf2f(u00.z) + wt.y * bf2f(u01.z) + wt.z * bf2f(u10.z) + wt.w * bf2f(u11.z);
                float v3 = wt.x * bf2f(u00.w) + wt.y * bf2f(u01.w) + wt.z * bf2f(u10.w) + wt.w * bf2f(u11.w);
                uint2 hv = make_uint2((unsigned)f2bf(v0) | ((unsigned)f2bf(v1) << 16),
                                      (unsigned)f2bf(v2) | ((unsigned)f2bf(v3) << 16));
                *(uint2*)&Vd[cidx * VSTR + cg * 4] = hv;
            }
        }
        __syncthreads();
    }

    // ---- combine group partials through LDS; group 0 stores ----
    float* F = (float*)V;   // 128 co x 32 px = 16 KB (V is free now)
    if (grp == 1) {
#pragma unroll
        for (int t = 0; t < 4; ++t)
#pragma unroll
            for (int p = 0; p < 2; ++p)
#pragma unroll
                for (int r = 0; r < 4; ++r)
                    F[(gw * 64 + t * 16 + q * 4 + r) * 32 + p * 16 + l15] = acc[t][p][r];
    }
    __syncthreads();
    if (grp == 0) {
#pragma unroll
        for (int t = 0; t < 4; ++t) {
#pragma unroll
            for (int r = 0; r < 4; ++r) {
                int col = gw * 64 + t * 16 + q * 4 + r;
                int co  = cog * 128 + col;
                float bias = bdcn[co];
#pragma unroll
                for (int p = 0; p < 2; ++p) {
                    int px = xh * 32 + p * 16 + l15;
                    out[(((size_t)b * COUT + co) << 12) + y * 64 + px]
                        = acc[t][p][r] + F[col * 32 + p * 16 + l15] + bias;
                }
            }
        }
    }
}

// ---------------------------------------------------------------------------
extern "C" void kernel_launch(void* const* d_in, const int* in_sizes, int n_in,
                              void* d_out, int out_size, void* d_ws, size_t ws_size,
                              hipStream_t stream)
{
    const float* x    = (const float*)d_in[0];
    const float* feat = (const float*)d_in[1];
    const float* wom  = (const float*)d_in[2];
    const float* bom  = (const float*)d_in[3];
    const float* wdcn = (const float*)d_in[4];
    const float* bdcn = (const float*)d_in[5];
    float* out = (float*)d_out;

    // workspace layout (all 16B-aligned)
    float* om12          = (float*)d_ws;                         // 12*2*27*4096 f32
    unsigned short* whi  = (unsigned short*)(om12 + (size_t)NKG * 2 * 27 * HWPIX);
    unsigned short* wohi = whi + (size_t)CKTOT * 256;            // 73728
    unsigned short* wolo = wohi + 73728;                         // 73728
    unsigned short* xTh  = wolo + 73728;                         // 2*4096*256
    unsigned short* fh   = xTh + (size_t)2 * HWPIX * 256;        // 2*4356*256
    unsigned short* fl   = fh + (size_t)2 * PHW * 256;           // 2*4356*256

    prep_kernel<<<7208, 256, 0, stream>>>(x, feat, wdcn, wom, xTh, fh, fl,
                                          whi, wohi, wolo);

    dim3 gco(64, NKG, 2);
    conv_om_mfma_kernel<<<gco, 256, 0, stream>>>(fh, fl, wohi, wolo, om12);

    dim3 grid(128, 2, 2);
    dcn_mfma_kernel<<<grid, 256, 0, stream>>>(xTh, om12, whi, bom, bdcn, out);
}

// Round 11
// 133.570 us; speedup vs baseline: 1.1613x; 1.1613x over previous
//
#include <hip/hip_runtime.h>
#include <math.h>

#define BATCH 2
#define CIN   256
#define COUT  256
#define COFF  256
#define HWPIX 4096
#define CKTOT 2304
#define VSTR  40            // V row stride in shorts (80 B)
#define PH    66            // padded feat spatial dim
#define PHW   4356          // 66*66
#define NKG   12            // conv_om K-split

typedef __attribute__((ext_vector_type(8))) short short8;
typedef __attribute__((ext_vector_type(8))) unsigned short ushort8;
typedef __attribute__((ext_vector_type(4))) float float4v;

__device__ __forceinline__ unsigned short f2bf(float f) {
    unsigned u = __float_as_uint(f);
    unsigned r = (u + 0x7FFFu + ((u >> 16) & 1u)) >> 16;   // RNE
    return (unsigned short)r;
}
__device__ __forceinline__ float bf2f(unsigned short h) {
    return __uint_as_float(((unsigned)h) << 16);
}

// ---------------------------------------------------------------------------
// prep: ONE kernel, blockIdx regions:
//   [0,2048)      x -> xTh (NHWC, bf16)
//   [2048,4096)   feat -> fh (NHWC, zero-padded 66x66, bf16)
//   [4096,6400)   wpack   (w_dcn -> whi, bf16, A-frag layout)
//   [6400,6688)   wpack_om(w_offset_mask -> wohi, M=32 padded, bf16)
//   [6688,7208)   zero fh borders (both batches)
// ---------------------------------------------------------------------------
__global__ __launch_bounds__(256) void prep_kernel(
    const float* __restrict__ x, const float* __restrict__ feat,
    const float* __restrict__ wdcn, const float* __restrict__ wom,
    unsigned short* __restrict__ xTh,
    unsigned short* __restrict__ fh,
    unsigned short* __restrict__ whi,
    unsigned short* __restrict__ wohi)
{
    const int bid = blockIdx.x;
    const int tid = threadIdx.x;

    if (bid < 4096) {
        const bool isx = bid < 2048;
        const int lb = isx ? bid : bid - 2048;
        const int b  = lb >> 10;
        const int r  = lb & 1023;
        const int pt = r >> 3;       // 128 px tiles of 32
        const int ct = r & 7;        // 8 ch tiles of 32
        __shared__ float t[32][33];
        const int tx = tid & 31, ty = tid >> 5;
        const float* src = isx ? x : feat;
        const float* sb = src + ((size_t)b * 256 + ct * 32) * HWPIX + pt * 32;
#pragma unroll
        for (int i = ty; i < 32; i += 8)
            t[i][tx] = sb[(size_t)i * HWPIX + tx];
        __syncthreads();
        if (isx) {
            unsigned short* ob = xTh + ((size_t)b * HWPIX + pt * 32) * 256 + ct * 32;
#pragma unroll
            for (int i = ty; i < 32; i += 8)
                ob[(size_t)i * 256 + tx] = f2bf(t[tx][i]);
        } else {
#pragma unroll
            for (int i = ty; i < 32; i += 8) {
                int p = pt * 32 + i;
                int row = (p >> 6) + 1, col = (p & 63) + 1;
                fh[((size_t)b * PHW + row * PH + col) * 256 + ct * 32 + tx]
                    = f2bf(t[tx][i]);
            }
        }
    } else if (bid < 6400) {
        int gid = (bid - 4096) * 256 + tid;    // 0..589823
        int cc  = gid & 31;
        int co  = (gid >> 5) & 255;
        int kcb = gid >> 13;
        int k   = kcb >> 3;
        int cb  = kcb & 7;
        float w = wdcn[((size_t)co * 256 + cb * 32 + cc) * 9 + k];
        whi[gid] = f2bf(w);
    } else if (bid < 6688) {
        int gid = (bid - 6400) * 256 + tid;    // 0..73727
        int cc  = gid & 31;
        int co  = (gid >> 5) & 31;
        int kcb = gid >> 10;
        int k   = kcb >> 3;
        int cb  = kcb & 7;
        float w = 0.0f;
        if (co < 27) w = wom[(size_t)co * CKTOT + (cb * 32 + cc) * 9 + k];
        wohi[gid] = f2bf(w);
    } else {
        int idx = (bid - 6688) * 256 + tid;    // < 133120 = 2*260*256 exactly
        int b = idx / 66560;
        int r = idx - b * 66560;
        int pidx = r >> 8;                     // 0..259 border cells
        int c = r & 255;
        int row, col;
        if (pidx < 66)       { row = 0;           col = pidx; }
        else if (pidx < 132) { row = 65;          col = pidx - 66; }
        else if (pidx < 196) { row = pidx - 131;  col = 0; }
        else                 { row = pidx - 195;  col = 65; }
        fh[((size_t)b * PHW + row * PH + col) * 256 + c] = 0;
    }
}

// ---------------------------------------------------------------------------
// conv_om via single-bf16 MFMA (precision budget spent: om needs ~0.4% rel).
// K-split x12; each kg writes its own partial plane om12[kg][b][27][4096].
// ---------------------------------------------------------------------------
__global__ __launch_bounds__(256) void conv_om_mfma_kernel(
    const unsigned short* __restrict__ fh,     // [2][4356][256] bf16
    const unsigned short* __restrict__ wohi,
    float* __restrict__ om12)                  // [12][2][27][4096]
{
    const int y  = blockIdx.x;     // 0..63
    const int kg = blockIdx.y;     // 0..11
    const int b  = blockIdx.z;
    const int tid = threadIdx.x;
    const int wv  = tid >> 6;
    const int lane = tid & 63;
    const int l15 = lane & 15;
    const int q   = lane >> 4;
    const int xg  = wv * 16 + l15;

    float4v acc[2];
    acc[0] = (float4v)0.0f;
    acc[1] = (float4v)0.0f;

    const unsigned short* fhb = fh + (size_t)b * PHW * 256;

#pragma unroll 3
    for (int i = 0; i < 6; ++i) {
        int kcb = kg * 6 + i;
        int k  = kcb >> 3;
        int cb = kcb & 7;
        size_t s = ((size_t)((y + k / 3) * PH + xg + k % 3)) * 256 + cb * 32 + q * 8;
        short8 bh = *(const short8*)(fhb + s);
        short8 ah0 = *(const short8*)(wohi + ((size_t)kcb * 32 + l15) * 32 + q * 8);
        short8 ah1 = *(const short8*)(wohi + ((size_t)kcb * 32 + 16 + l15) * 32 + q * 8);
        acc[0] = __builtin_amdgcn_mfma_f32_16x16x32_bf16(ah0, bh, acc[0], 0, 0, 0);
        acc[1] = __builtin_amdgcn_mfma_f32_16x16x32_bf16(ah1, bh, acc[1], 0, 0, 0);
    }

    const int p = y * 64 + xg;
    float* ob = om12 + (size_t)(kg * 2 + b) * 27 * HWPIX;
#pragma unroll
    for (int t = 0; t < 2; ++t) {
#pragma unroll
        for (int r = 0; r < 4; ++r) {
            int co = t * 16 + q * 4 + r;
            if (co < 27) ob[co * HWPIX + p] = acc[t][r];
        }
    }
}

// ---------------------------------------------------------------------------
// dcn v9: r9 barrier structure (best known, 49us), staging with 16B gathers:
// 8 ch/thread, taps split across thread-halves -> ~4.5 latency windows per
// thread per cb (was 9). Tile 128co x 32px; grid (128,2,2) = 512 blocks.
// ---------------------------------------------------------------------------
__global__ __launch_bounds__(256) void dcn_mfma_kernel(
    const unsigned short* __restrict__ xTh,    // [2][4096][256] bf16
    const float* __restrict__ om12,            // [12][2][27][4096]
    const unsigned short* __restrict__ whi,    // [72][256][32] bf16
    const float* __restrict__ bom,             // [27]
    const float* __restrict__ bdcn,            // [256]
    float* __restrict__ out)                   // [2][256][4096]
{
    const int tid = threadIdx.x;
    const int y   = blockIdx.x >> 1;           // 0..63
    const int xh  = blockIdx.x & 1;            // 0..1 (32-px halves)
    const int cog = blockIdx.y;                // 0..1 (co halves)
    const int b   = blockIdx.z;

    __shared__ float4 s_wt[288];               // masked bilinear weights
    __shared__ int4   s_ix[288];               // clamped corner indices
    __shared__ unsigned short V[288 * VSTR];   // B tiles [k*32+px][ch]

    // ---- prologue: sum 12 om partials + bias; bilinear weights + indices ----
    for (int idx = tid; idx < 288; idx += 256) {
        int k   = idx >> 5;
        int pxl = idx & 31;
        int xg  = xh * 32 + pxl;
        int p   = y * 64 + xg;
        float dy = bom[2 * k], dx = bom[2 * k + 1], mm = bom[18 + k];
#pragma unroll
        for (int g = 0; g < NKG; ++g) {
            const float* ob = om12 + (size_t)(g * 2 + b) * 27 * HWPIX;
            dy += ob[(2 * k) * HWPIX + p];
            dx += ob[(2 * k + 1) * HWPIX + p];
            mm += ob[(18 + k) * HWPIX + p];
        }
        float ys = (float)(y  - 1 + (k / 3)) + dy;
        float xs = (float)(xg - 1 + (k % 3)) + dx;
        float y0f = floorf(ys), x0f = floorf(xs);
        int y0 = (int)y0f, x0 = (int)x0f;
        float ly = ys - y0f, lx = xs - x0f;
        float m  = 1.0f / (1.0f + expf(-mm));
        bool yv0 = ((unsigned)y0 < 64u), yv1 = ((unsigned)(y0 + 1) < 64u);
        bool xv0 = ((unsigned)x0 < 64u), xv1 = ((unsigned)(x0 + 1) < 64u);
        int i00 = y0 * 64 + x0;
        float4 wt;
        int4 ix;
        wt.x = (yv0 && xv0) ? (1.0f - ly) * (1.0f - lx) * m : 0.0f;
        wt.y = (yv0 && xv1) ? (1.0f - ly) * lx * m          : 0.0f;
        wt.z = (yv1 && xv0) ? ly * (1.0f - lx) * m          : 0.0f;
        wt.w = (yv1 && xv1) ? ly * lx * m                   : 0.0f;
        ix.x = (yv0 && xv0) ? i00      : 0;
        ix.y = (yv0 && xv1) ? i00 + 1  : 0;
        ix.z = (yv1 && xv0) ? i00 + 64 : 0;
        ix.w = (yv1 && xv1) ? i00 + 65 : 0;
        s_wt[idx] = wt;
        s_ix[idx] = ix;
    }
    __syncthreads();

    const int w    = tid >> 6;     // wave -> co base cog*128 + w*32
    const int lane = tid & 63;
    const int l15  = lane & 15;
    const int q    = lane >> 4;

    // staging map: cg = tid&3 (8 ch), spx = (tid>>2)&31, tapg = tid>>7
    const int cg   = tid & 3;
    const int spx  = (tid >> 2) & 31;
    const int tapg = tid >> 7;     // 0: taps 0,2,4,6,8  1: taps 1,3,5,7

    float4v acc[2][2];
#pragma unroll
    for (int t = 0; t < 2; ++t)
#pragma unroll
        for (int p = 0; p < 2; ++p) acc[t][p] = (float4v)0.0f;

    const unsigned short* xb = xTh + ((size_t)b << 12) * 256;

    for (int cb = 0; cb < 8; ++cb) {
        // ---- stage: ~4.5 taps x 32 px x 8 ch per thread (16B gathers) ----
        {
            const unsigned short* xc = xb + cb * 32 + cg * 8;
#pragma unroll 3
            for (int j = 0; j < 5; ++j) {
                int k = 2 * j + tapg;
                if (k > 8) break;
                int cidx = k * 32 + spx;
                float4 wt = s_wt[cidx];
                int4   ix = s_ix[cidx];
                ushort8 u00 = *(const ushort8*)(xc + (size_t)ix.x * 256);
                ushort8 u01 = *(const ushort8*)(xc + (size_t)ix.y * 256);
                ushort8 u10 = *(const ushort8*)(xc + (size_t)ix.z * 256);
                ushort8 u11 = *(const ushort8*)(xc + (size_t)ix.w * 256);
                unsigned hv[4];
#pragma unroll
                for (int jj = 0; jj < 4; ++jj) {
                    float va = wt.x * bf2f(u00[2 * jj])     + wt.y * bf2f(u01[2 * jj])
                             + wt.z * bf2f(u10[2 * jj])     + wt.w * bf2f(u11[2 * jj]);
                    float vb = wt.x * bf2f(u00[2 * jj + 1]) + wt.y * bf2f(u01[2 * jj + 1])
                             + wt.z * bf2f(u10[2 * jj + 1]) + wt.w * bf2f(u11[2 * jj + 1]);
                    hv[jj] = (unsigned)f2bf(va) | ((unsigned)f2bf(vb) << 16);
                }
                *(uint4*)&V[cidx * VSTR + cg * 8]
                    = make_uint4(hv[0], hv[1], hv[2], hv[3]);
            }
        }
        __syncthreads();

        // ---- 9 MFMA chunks on this cb: 2 A-loads + 2 ds + 4 MFMA each ----
#pragma unroll 3
        for (int k = 0; k < 9; ++k) {
            const int kcb = k * 8 + cb;
            size_t base = ((size_t)kcb * 256 + cog * 128 + w * 32 + l15) * 32 + q * 8;
            short8 ah0 = *(const short8*)(whi + base);
            short8 ah1 = *(const short8*)(whi + base + 16 * 32);
            short8 bh0 = *(const short8*)&V[(k * 32 + l15) * VSTR + q * 8];
            short8 bh1 = *(const short8*)&V[(k * 32 + 16 + l15) * VSTR + q * 8];
            acc[0][0] = __builtin_amdgcn_mfma_f32_16x16x32_bf16(ah0, bh0, acc[0][0], 0, 0, 0);
            acc[0][1] = __builtin_amdgcn_mfma_f32_16x16x32_bf16(ah0, bh1, acc[0][1], 0, 0, 0);
            acc[1][0] = __builtin_amdgcn_mfma_f32_16x16x32_bf16(ah1, bh0, acc[1][0], 0, 0, 0);
            acc[1][1] = __builtin_amdgcn_mfma_f32_16x16x32_bf16(ah1, bh1, acc[1][1], 0, 0, 0);
        }
        __syncthreads();
    }

    // ---- epilogue: plain stores (D: row co = q*4+r, col px = l15) ----
#pragma unroll
    for (int t = 0; t < 2; ++t) {
#pragma unroll
        for (int r = 0; r < 4; ++r) {
            int co = cog * 128 + w * 32 + t * 16 + q * 4 + r;
            float bias = bdcn[co];
#pragma unroll
            for (int p = 0; p < 2; ++p) {
                int px = xh * 32 + p * 16 + l15;
                out[(((size_t)b * COUT + co) << 12) + y * 64 + px]
                    = acc[t][p][r] + bias;
            }
        }
    }
}

// ---------------------------------------------------------------------------
extern "C" void kernel_launch(void* const* d_in, const int* in_sizes, int n_in,
                              void* d_out, int out_size, void* d_ws, size_t ws_size,
                              hipStream_t stream)
{
    const float* x    = (const float*)d_in[0];
    const float* feat = (const float*)d_in[1];
    const float* wom  = (const float*)d_in[2];
    const float* bom  = (const float*)d_in[3];
    const float* wdcn = (const float*)d_in[4];
    const float* bdcn = (const float*)d_in[5];
    float* out = (float*)d_out;

    // workspace layout (all 16B-aligned)
    float* om12          = (float*)d_ws;                         // 12*2*27*4096 f32
    unsigned short* whi  = (unsigned short*)(om12 + (size_t)NKG * 2 * 27 * HWPIX);
    unsigned short* wohi = whi + (size_t)CKTOT * 256;            // 73728
    unsigned short* xTh  = wohi + 73728;                         // 2*4096*256
    unsigned short* fh   = xTh + (size_t)2 * HWPIX * 256;        // 2*4356*256

    prep_kernel<<<7208, 256, 0, stream>>>(x, feat, wdcn, wom, xTh, fh,
                                          whi, wohi);

    dim3 gco(64, NKG, 2);
    conv_om_mfma_kernel<<<gco, 256, 0, stream>>>(fh, wohi, om12);

    dim3 grid(128, 2, 2);
    dcn_mfma_kernel<<<grid, 256, 0, stream>>>(xTh, om12, whi, bom, bdcn, out);
}